// Round 1
// baseline (127.993 us; speedup 1.0000x reference)
//
#include <hip/hip_runtime.h>
#include <hip/hip_bf16.h>
#include <math.h>

#define B_ 2
#define S_ 2048
#define M_ 1024
#define R_ 64
#define N_ 16
#define NC 64          // s-chunks
#define CH (S_/NC)     // 32

// ws float offsets
#define DT_OFF  0
#define BP_OFF  4194304
#define CP_OFF  4259840
#define BWT_OFF 4325376
#define CWT_OFF 4341760
#define P_OFF   4358144
// total 8552448 floats = 32.6 MiB

__global__ __launch_bounds__(256) void k_transpose(const float* __restrict__ Bw,
                                                   const float* __restrict__ Cw,
                                                   float* __restrict__ BwT,
                                                   float* __restrict__ CwT) {
    int idx = blockIdx.x * 256 + threadIdx.x;          // 0..16383
    if (idx >= M_ * N_) return;
    int m = idx >> 4, n = idx & 15;
    BwT[idx] = Bw[n * M_ + m];
    CwT[idx] = Cw[n * M_ + m];
}

// dt = clip(softplus(delta @ Wdt^T + bdt), 1e-6, 10)
__global__ __launch_bounds__(256) void k_dt(const float* __restrict__ delta,
                                            const float* __restrict__ Wdt,
                                            const float* __restrict__ bdt,
                                            float* __restrict__ dt) {
    int m    = blockIdx.x * 256 + threadIdx.x;         // 0..1023
    int row0 = blockIdx.y * 32;                        // bs base
    float w[R_];
    const float4* W4 = reinterpret_cast<const float4*>(Wdt + m * R_);
#pragma unroll
    for (int i = 0; i < R_ / 4; ++i) {
        float4 v = W4[i];
        w[4*i] = v.x; w[4*i+1] = v.y; w[4*i+2] = v.z; w[4*i+3] = v.w;
    }
    float bias = bdt[m];
    for (int r = 0; r < 32; ++r) {
        int bs = row0 + r;
        const float* dr = delta + bs * R_;             // wave-uniform -> s_load
        float acc = bias;
#pragma unroll
        for (int k = 0; k < R_; ++k) acc = fmaf(dr[k], w[k], acc);
        float sp = fmaxf(acc, 0.f) + log1pf(expf(-fabsf(acc)));
        sp = fminf(fmaxf(sp, 1e-6f), 10.0f);
        dt[bs * M_ + m] = sp;
    }
}

// B = u @ BwT, C = u @ CwT   (per block: 16 bs-rows, u staged in LDS)
__global__ __launch_bounds__(256) void k_bc(const float* __restrict__ u,
                                            const float* __restrict__ BwT,
                                            const float* __restrict__ CwT,
                                            float* __restrict__ Bp,
                                            float* __restrict__ Cp) {
    __shared__ float uLds[16 * 1024];                  // 64 KiB
    int base = blockIdx.x * 16;
    for (int i = threadIdx.x; i < 16 * 1024; i += 256)
        uLds[i] = u[base * M_ + i];
    __syncthreads();
    int r = threadIdx.x >> 4, n = threadIdx.x & 15;
    const float4* u4 = reinterpret_cast<const float4*>(uLds + r * 1024);
    float accB = 0.f, accC = 0.f;
#pragma unroll 4
    for (int m4 = 0; m4 < 256; ++m4) {
        float4 uv = u4[m4];
        int mb = m4 * 4;
        accB = fmaf(uv.x, BwT[(mb+0)*16 + n], accB);
        accB = fmaf(uv.y, BwT[(mb+1)*16 + n], accB);
        accB = fmaf(uv.z, BwT[(mb+2)*16 + n], accB);
        accB = fmaf(uv.w, BwT[(mb+3)*16 + n], accB);
        accC = fmaf(uv.x, CwT[(mb+0)*16 + n], accC);
        accC = fmaf(uv.y, CwT[(mb+1)*16 + n], accC);
        accC = fmaf(uv.z, CwT[(mb+2)*16 + n], accC);
        accC = fmaf(uv.w, CwT[(mb+3)*16 + n], accC);
    }
    Bp[(base + r) * N_ + n] = accB;
    Cp[(base + r) * N_ + n] = accC;
}

__device__ __forceinline__ void load_row16(const float* __restrict__ p, float* dst) {
    const float4* p4 = reinterpret_cast<const float4*>(p);
#pragma unroll
    for (int i = 0; i < 4; ++i) {
        float4 v = p4[i];
        dst[4*i] = v.x; dst[4*i+1] = v.y; dst[4*i+2] = v.z; dst[4*i+3] = v.w;
    }
}

// pass1: per-chunk sums of a (=log dA) and dBu/dA
__global__ __launch_bounds__(256) void k_pass1(const float* __restrict__ dt,
                                               const float* __restrict__ u,
                                               const float* __restrict__ Bp,
                                               const float* __restrict__ A_log,
                                               float* __restrict__ P) {
    int m = blockIdx.x * 256 + threadIdx.x;
    int c = blockIdx.y, b = blockIdx.z;
    float Aa[N_];
#pragma unroll
    for (int n = 0; n < N_; ++n) {
        float a = -expf(A_log[n * M_ + m]);
        Aa[n] = fminf(fmaxf(a, -10.f), -1e-6f);
    }
    float sL[N_], sS[N_];
#pragma unroll
    for (int n = 0; n < N_; ++n) { sL[n] = 0.f; sS[n] = 0.f; }
    int s0 = c * CH;
    for (int i = 0; i < CH; ++i) {
        int s = s0 + i;
        int off = (b * S_ + s) * M_ + m;
        float dtv = dt[off], uv = u[off];
        float du = dtv * uv;
        float bv[N_];
        load_row16(Bp + (b * S_ + s) * N_, bv);
#pragma unroll
        for (int n = 0; n < N_; ++n) {
            float a = dtv * Aa[n];
            sL[n] += a;
            sS[n] = fmaf(du * bv[n], __expf(-a), sS[n]);
        }
    }
#pragma unroll
    for (int n = 0; n < N_; ++n) {
        P[((b * 32 + n)      * NC + c) * M_ + m] = sL[n];
        P[((b * 32 + 16 + n) * NC + c) * M_ + m] = sS[n];
    }
}

// pass2: exclusive prefix over the NC chunk aggregates, in place
__global__ __launch_bounds__(256) void k_scanchunks(float* __restrict__ P) {
    int x = blockIdx.x * 256 + threadIdx.x;            // 65536 threads
    int m = x & (M_ - 1);
    int j = (x >> 10) & 31;
    int b = x >> 15;
    int base = ((b * 32 + j) * NC) * M_ + m;
    float run = 0.f;
    for (int c = 0; c < NC; ++c) {
        float v = P[base + c * M_];
        P[base + c * M_] = run;
        run += v;
    }
}

// pass3: within-chunk scan, h = exp(L)*S, y = sum_n h*C, out = clip(y + u*D)
__global__ __launch_bounds__(256) void k_pass3(const float* __restrict__ dt,
                                               const float* __restrict__ u,
                                               const float* __restrict__ Bp,
                                               const float* __restrict__ Cp,
                                               const float* __restrict__ A_log,
                                               const float* __restrict__ Dskip,
                                               const float* __restrict__ P,
                                               float* __restrict__ out) {
    int m = blockIdx.x * 256 + threadIdx.x;
    int c = blockIdx.y, b = blockIdx.z;
    float Aa[N_];
#pragma unroll
    for (int n = 0; n < N_; ++n) {
        float a = -expf(A_log[n * M_ + m]);
        Aa[n] = fminf(fmaxf(a, -10.f), -1e-6f);
    }
    float L[N_], Sv[N_];
#pragma unroll
    for (int n = 0; n < N_; ++n) {
        L[n]  = P[((b * 32 + n)      * NC + c) * M_ + m];
        Sv[n] = P[((b * 32 + 16 + n) * NC + c) * M_ + m];
    }
    float Dm = Dskip[m];
    int s0 = c * CH;
    for (int i = 0; i < CH; ++i) {
        int s = s0 + i;
        int off = (b * S_ + s) * M_ + m;
        float dtv = dt[off], uv = u[off];
        float du = dtv * uv;
        float bv[N_], cv[N_];
        load_row16(Bp + (b * S_ + s) * N_, bv);
        load_row16(Cp + (b * S_ + s) * N_, cv);
        float y = 0.f;
#pragma unroll
        for (int n = 0; n < N_; ++n) {
            float a = dtv * Aa[n];
            L[n] += a;                                  // log dA_c == a (clip inactive)
            Sv[n] = fmaf(du * bv[n], __expf(-a), Sv[n]);
            y = fmaf(__expf(L[n]) * Sv[n], cv[n], y);
        }
        float o = y + uv * Dm;
        o = fminf(fmaxf(o, -10000.f), 10000.f);
        out[off] = o;
    }
}

extern "C" void kernel_launch(void* const* d_in, const int* in_sizes, int n_in,
                              void* d_out, int out_size, void* d_ws, size_t ws_size,
                              hipStream_t stream) {
    const float* u     = (const float*)d_in[0];
    const float* delta = (const float*)d_in[1];
    const float* Wdt   = (const float*)d_in[2];
    const float* bdt   = (const float*)d_in[3];
    const float* A_log = (const float*)d_in[4];
    const float* Dski  = (const float*)d_in[5];
    const float* Bw    = (const float*)d_in[6];
    const float* Cw    = (const float*)d_in[7];
    float* out = (float*)d_out;
    float* ws  = (float*)d_ws;

    float* dt  = ws + DT_OFF;
    float* Bp  = ws + BP_OFF;
    float* Cp  = ws + CP_OFF;
    float* BwT = ws + BWT_OFF;
    float* CwT = ws + CWT_OFF;
    float* P   = ws + P_OFF;

    k_transpose<<<64, 256, 0, stream>>>(Bw, Cw, BwT, CwT);
    k_dt<<<dim3(4, 128), 256, 0, stream>>>(delta, Wdt, bdt, dt);
    k_bc<<<256, 256, 0, stream>>>(u, BwT, CwT, Bp, Cp);
    k_pass1<<<dim3(4, NC, B_), 256, 0, stream>>>(dt, u, Bp, A_log, P);
    k_scanchunks<<<256, 256, 0, stream>>>(P);
    k_pass3<<<dim3(4, NC, B_), 256, 0, stream>>>(dt, u, Bp, Cp, A_log, Dski, P, out);
}

// Round 2
// 126.753 us; speedup vs baseline: 1.0098x; 1.0098x over previous
//
#include <hip/hip_runtime.h>
#include <hip/hip_bf16.h>
#include <math.h>

#define B_ 2
#define S_ 2048
#define M_ 1024
#define R_ 64
#define N_ 16
#define NC 64          // s-chunks
#define CH (S_/NC)     // 32

// ws float offsets
#define DT_OFF  0
#define BP_OFF  4194304
#define CP_OFF  4259840
#define BWT_OFF 4325376
#define CWT_OFF 4341760
#define P_OFF   4358144
// total 8552448 floats = 32.6 MiB

__global__ __launch_bounds__(256) void k_transpose(const float* __restrict__ Bw,
                                                   const float* __restrict__ Cw,
                                                   float* __restrict__ BwT,
                                                   float* __restrict__ CwT) {
    int idx = blockIdx.x * 256 + threadIdx.x;          // 0..16383
    if (idx >= M_ * N_) return;
    int m = idx >> 4, n = idx & 15;
    BwT[idx] = Bw[n * M_ + m];
    CwT[idx] = Cw[n * M_ + m];
}

// dt = clip(softplus(delta @ Wdt^T + bdt), 1e-6, 10)
__global__ __launch_bounds__(256) void k_dt(const float* __restrict__ delta,
                                            const float* __restrict__ Wdt,
                                            const float* __restrict__ bdt,
                                            float* __restrict__ dt) {
    int m    = blockIdx.x * 256 + threadIdx.x;         // 0..1023
    int row0 = blockIdx.y * 32;                        // bs base
    float w[R_];
    const float4* W4 = reinterpret_cast<const float4*>(Wdt + m * R_);
#pragma unroll
    for (int i = 0; i < R_ / 4; ++i) {
        float4 v = W4[i];
        w[4*i] = v.x; w[4*i+1] = v.y; w[4*i+2] = v.z; w[4*i+3] = v.w;
    }
    float bias = bdt[m];
    for (int r = 0; r < 32; ++r) {
        int bs = row0 + r;
        const float* dr = delta + bs * R_;             // wave-uniform -> s_load
        float acc = bias;
#pragma unroll
        for (int k = 0; k < R_; ++k) acc = fmaf(dr[k], w[k], acc);
        float sp = fmaxf(acc, 0.f) + log1pf(expf(-fabsf(acc)));
        sp = fminf(fmaxf(sp, 1e-6f), 10.0f);
        dt[bs * M_ + m] = sp;
    }
}

// B = u @ BwT, C = u @ CwT   (per block: 16 bs-rows, u staged in LDS)
__global__ __launch_bounds__(256) void k_bc(const float* __restrict__ u,
                                            const float* __restrict__ BwT,
                                            const float* __restrict__ CwT,
                                            float* __restrict__ Bp,
                                            float* __restrict__ Cp) {
    __shared__ float uLds[16 * 1024];                  // 64 KiB
    int base = blockIdx.x * 16;
    for (int i = threadIdx.x; i < 16 * 1024; i += 256)
        uLds[i] = u[base * M_ + i];
    __syncthreads();
    int r = threadIdx.x >> 4, n = threadIdx.x & 15;
    const float4* u4 = reinterpret_cast<const float4*>(uLds + r * 1024);
    float accB = 0.f, accC = 0.f;
#pragma unroll 4
    for (int m4 = 0; m4 < 256; ++m4) {
        float4 uv = u4[m4];
        int mb = m4 * 4;
        accB = fmaf(uv.x, BwT[(mb+0)*16 + n], accB);
        accB = fmaf(uv.y, BwT[(mb+1)*16 + n], accB);
        accB = fmaf(uv.z, BwT[(mb+2)*16 + n], accB);
        accB = fmaf(uv.w, BwT[(mb+3)*16 + n], accB);
        accC = fmaf(uv.x, CwT[(mb+0)*16 + n], accC);
        accC = fmaf(uv.y, CwT[(mb+1)*16 + n], accC);
        accC = fmaf(uv.z, CwT[(mb+2)*16 + n], accC);
        accC = fmaf(uv.w, CwT[(mb+3)*16 + n], accC);
    }
    Bp[(base + r) * N_ + n] = accB;
    Cp[(base + r) * N_ + n] = accC;
}

__device__ __forceinline__ void load_row16(const float* __restrict__ p, float* dst) {
    const float4* p4 = reinterpret_cast<const float4*>(p);
#pragma unroll
    for (int i = 0; i < 4; ++i) {
        float4 v = p4[i];
        dst[4*i] = v.x; dst[4*i+1] = v.y; dst[4*i+2] = v.z; dst[4*i+3] = v.w;
    }
}

// pass1: per-chunk sums of a (=log dA) and dBu/dA
__global__ __launch_bounds__(256) void k_pass1(const float* __restrict__ dt,
                                               const float* __restrict__ u,
                                               const float* __restrict__ Bp,
                                               const float* __restrict__ A_log,
                                               float* __restrict__ P) {
    int m = blockIdx.x * 256 + threadIdx.x;
    int c = blockIdx.y, b = blockIdx.z;
    float Aa[N_];
#pragma unroll
    for (int n = 0; n < N_; ++n) {
        float a = -expf(A_log[n * M_ + m]);
        Aa[n] = fminf(fmaxf(a, -10.f), -1e-6f);
    }
    float sL[N_], sS[N_];
#pragma unroll
    for (int n = 0; n < N_; ++n) { sL[n] = 0.f; sS[n] = 0.f; }
    int s0 = c * CH;
    for (int i = 0; i < CH; ++i) {
        int s = s0 + i;
        int off = (b * S_ + s) * M_ + m;
        float dtv = dt[off], uv = u[off];
        float du = dtv * uv;
        float bv[N_];
        load_row16(Bp + (b * S_ + s) * N_, bv);
#pragma unroll
        for (int n = 0; n < N_; ++n) {
            float a = dtv * Aa[n];
            sL[n] += a;
            sS[n] = fmaf(du * bv[n], __expf(-a), sS[n]);
        }
    }
#pragma unroll
    for (int n = 0; n < N_; ++n) {
        P[((b * 32 + n)      * NC + c) * M_ + m] = sL[n];
        P[((b * 32 + 16 + n) * NC + c) * M_ + m] = sS[n];
    }
}

// pass2: exclusive prefix over the NC chunk aggregates, in place
__global__ __launch_bounds__(256) void k_scanchunks(float* __restrict__ P) {
    int x = blockIdx.x * 256 + threadIdx.x;            // 65536 threads
    int m = x & (M_ - 1);
    int j = (x >> 10) & 31;
    int b = x >> 15;
    int base = ((b * 32 + j) * NC) * M_ + m;
    float run = 0.f;
    for (int c = 0; c < NC; ++c) {
        float v = P[base + c * M_];
        P[base + c * M_] = run;
        run += v;
    }
}

// pass3: within-chunk scan, h = exp(L)*S, y = sum_n h*C, out = clip(y + u*D)
__global__ __launch_bounds__(256) void k_pass3(const float* __restrict__ dt,
                                               const float* __restrict__ u,
                                               const float* __restrict__ Bp,
                                               const float* __restrict__ Cp,
                                               const float* __restrict__ A_log,
                                               const float* __restrict__ Dskip,
                                               const float* __restrict__ P,
                                               float* __restrict__ out) {
    int m = blockIdx.x * 256 + threadIdx.x;
    int c = blockIdx.y, b = blockIdx.z;
    float Aa[N_];
#pragma unroll
    for (int n = 0; n < N_; ++n) {
        float a = -expf(A_log[n * M_ + m]);
        Aa[n] = fminf(fmaxf(a, -10.f), -1e-6f);
    }
    float L[N_], Sv[N_];
#pragma unroll
    for (int n = 0; n < N_; ++n) {
        L[n]  = P[((b * 32 + n)      * NC + c) * M_ + m];
        Sv[n] = P[((b * 32 + 16 + n) * NC + c) * M_ + m];
    }
    float Dm = Dskip[m];
    int s0 = c * CH;
    for (int i = 0; i < CH; ++i) {
        int s = s0 + i;
        int off = (b * S_ + s) * M_ + m;
        float dtv = dt[off], uv = u[off];
        float du = dtv * uv;
        float bv[N_], cv[N_];
        load_row16(Bp + (b * S_ + s) * N_, bv);
        load_row16(Cp + (b * S_ + s) * N_, cv);
        float y = 0.f;
#pragma unroll
        for (int n = 0; n < N_; ++n) {
            float a = dtv * Aa[n];
            L[n] += a;                                  // log dA_c == a (clip inactive)
            Sv[n] = fmaf(du * bv[n], __expf(-a), Sv[n]);
            y = fmaf(__expf(L[n]) * Sv[n], cv[n], y);
        }
        float o = y + uv * Dm;
        o = fminf(fmaxf(o, -10000.f), 10000.f);
        out[off] = o;
    }
}

extern "C" void kernel_launch(void* const* d_in, const int* in_sizes, int n_in,
                              void* d_out, int out_size, void* d_ws, size_t ws_size,
                              hipStream_t stream) {
    const float* u     = (const float*)d_in[0];
    const float* delta = (const float*)d_in[1];
    const float* Wdt   = (const float*)d_in[2];
    const float* bdt   = (const float*)d_in[3];
    const float* A_log = (const float*)d_in[4];
    const float* Dski  = (const float*)d_in[5];
    const float* Bw    = (const float*)d_in[6];
    const float* Cw    = (const float*)d_in[7];
    float* out = (float*)d_out;
    float* ws  = (float*)d_ws;

    float* dt  = ws + DT_OFF;
    float* Bp  = ws + BP_OFF;
    float* Cp  = ws + CP_OFF;
    float* BwT = ws + BWT_OFF;
    float* CwT = ws + CWT_OFF;
    float* P   = ws + P_OFF;

    k_transpose<<<64, 256, 0, stream>>>(Bw, Cw, BwT, CwT);
    k_dt<<<dim3(4, 128), 256, 0, stream>>>(delta, Wdt, bdt, dt);
    k_bc<<<256, 256, 0, stream>>>(u, BwT, CwT, Bp, Cp);
    k_pass1<<<dim3(4, NC, B_), 256, 0, stream>>>(dt, u, Bp, A_log, P);
    k_scanchunks<<<256, 256, 0, stream>>>(P);
    k_pass3<<<dim3(4, NC, B_), 256, 0, stream>>>(dt, u, Bp, Cp, A_log, Dski, P, out);
}

// Round 4
// 114.722 us; speedup vs baseline: 1.1157x; 1.1049x over previous
//
#include <hip/hip_runtime.h>
#include <hip/hip_bf16.h>
#include <math.h>

#define B_ 2
#define S_ 2048
#define M_ 1024
#define R_ 64
#define N_ 16
#define NC 64          // s-chunks
#define CH (S_/NC)     // 32

// ws float offsets
#define DT_OFF  0                    // 4,194,304
#define P_OFF   4194304              // 2,097,152  chunk prod of e^a -> g_init
#define H_OFF   6291456              // 2,097,152  Hloc -> h_init
#define BP_OFF  8388608              // 65,536
#define CP_OFF  8454144              // 65,536
#define BWT_OFF 8519680              // 16,384
#define CWT_OFF 8536064              // 16,384
#define PB_OFF  8552448              // 262,144 (4 k-split partials, B)
#define PC_OFF  8814592              // 262,144 (C)
// total 9,076,736 floats = 36.3 MiB

__global__ __launch_bounds__(256) void k_prep(const float* __restrict__ Bw,
                                              const float* __restrict__ Cw,
                                              float* __restrict__ BwT,
                                              float* __restrict__ CwT) {
    int idx = blockIdx.x * 256 + threadIdx.x;          // 0..16383
    int m = idx >> 4, n = idx & 15;
    BwT[idx] = Bw[n * M_ + m];
    CwT[idx] = Cw[n * M_ + m];
}

// dt = clip(softplus(delta @ Wdt^T + bdt), 1e-6, 10); grid (4, 512)
__global__ __launch_bounds__(256) void k_dt(const float* __restrict__ delta,
                                            const float* __restrict__ Wdt,
                                            const float* __restrict__ bdt,
                                            float* __restrict__ dt) {
    int m    = blockIdx.x * 256 + threadIdx.x;         // 0..1023
    int row0 = blockIdx.y * 8;                         // bs base
    float w[R_];
    const float4* W4 = reinterpret_cast<const float4*>(Wdt + (size_t)m * R_);
#pragma unroll
    for (int i = 0; i < R_ / 4; ++i) {
        float4 v = W4[i];
        w[4*i] = v.x; w[4*i+1] = v.y; w[4*i+2] = v.z; w[4*i+3] = v.w;
    }
    float bias = bdt[m];
#pragma unroll 1
    for (int r = 0; r < 8; ++r) {
        int bs = row0 + r;
        const float* dr = delta + (size_t)bs * R_;     // wave-uniform -> s_load
        float acc = bias;
#pragma unroll
        for (int k = 0; k < R_; ++k) acc = fmaf(dr[k], w[k], acc);
        float sp = fmaxf(acc, 0.f) + log1pf(expf(-fabsf(acc)));
        sp = fminf(fmaxf(sp, 1e-6f), 10.0f);
        dt[(size_t)bs * M_ + m] = sp;
    }
}

// B/C projection, K-split partials; grid (256 row-groups, 4 k-splits)
__global__ __launch_bounds__(256) void k_bc_partial(const float* __restrict__ u,
                                                    const float* __restrict__ BwT,
                                                    const float* __restrict__ CwT,
                                                    float* __restrict__ pB,
                                                    float* __restrict__ pC) {
    __shared__ float uLds[16 * 260];                   // padded: stride 260
    int r0 = blockIdx.x * 16;
    int k0 = blockIdx.y * 256;
    for (int i = threadIdx.x; i < 4096; i += 256) {
        int r = i >> 8, k = i & 255;
        uLds[r * 260 + k] = u[(size_t)(r0 + r) * M_ + k0 + k];
    }
    __syncthreads();
    int r = threadIdx.x >> 4, n = threadIdx.x & 15;
    const float4* u4 = reinterpret_cast<const float4*>(uLds + r * 260);
    float accB = 0.f, accC = 0.f;
#pragma unroll 4
    for (int k4 = 0; k4 < 64; ++k4) {
        float4 uv = u4[k4];
        int kb = k0 + k4 * 4;
        accB = fmaf(uv.x, BwT[(kb+0)*16 + n], accB);
        accB = fmaf(uv.y, BwT[(kb+1)*16 + n], accB);
        accB = fmaf(uv.z, BwT[(kb+2)*16 + n], accB);
        accB = fmaf(uv.w, BwT[(kb+3)*16 + n], accB);
        accC = fmaf(uv.x, CwT[(kb+0)*16 + n], accC);
        accC = fmaf(uv.y, CwT[(kb+1)*16 + n], accC);
        accC = fmaf(uv.z, CwT[(kb+2)*16 + n], accC);
        accC = fmaf(uv.w, CwT[(kb+3)*16 + n], accC);
    }
    size_t o = (size_t)blockIdx.y * 65536 + (size_t)(r0 + r) * 16 + n;
    pB[o] = accB;
    pC[o] = accC;
}

__global__ __launch_bounds__(256) void k_bc_reduce(const float* __restrict__ pB,
                                                   const float* __restrict__ pC,
                                                   float* __restrict__ Bp,
                                                   float* __restrict__ Cp) {
    int idx = blockIdx.x * 256 + threadIdx.x;          // 0..65535
    float sB = 0.f, sC = 0.f;
#pragma unroll
    for (int ks = 0; ks < 4; ++ks) {
        sB += pB[(size_t)ks * 65536 + idx];
        sC += pC[(size_t)ks * 65536 + idx];
    }
    Bp[idx] = sB;
    Cp[idx] = sC;
}

// pass1: per-chunk Pc = prod(e^a) and Hloc from (g=1, h=0):
//   ea = e^a; h = ea*h + g*du*b; g *= ea          (exact reference semantics:
//   h_t = e^{L_t} * sum dbu_tau e^{-a_tau})
// grid (16, NC, B_), block 256; 4 n-states per thread
__global__ __launch_bounds__(256) void k_pass1(const float* __restrict__ dt,
                                               const float* __restrict__ u,
                                               const float* __restrict__ Bp,
                                               const float* __restrict__ A_log,
                                               float* __restrict__ P,
                                               float* __restrict__ H) {
    __shared__ float ldsDt[CH * 64], ldsU[CH * 64], ldsB[CH * 16];
    int m0 = blockIdx.x * 64, c = blockIdx.y, b = blockIdx.z;
    int s0 = c * CH;
    int tid = threadIdx.x;
    for (int i = tid; i < CH * 64; i += 256) {
        int s = i >> 6, ml = i & 63;
        size_t off = ((size_t)(b * S_ + s0 + s)) * M_ + m0 + ml;
        ldsDt[i] = dt[off];
        ldsU[i]  = u[off];
    }
    for (int i = tid; i < CH * 16; i += 256)
        ldsB[i] = Bp[(size_t)(b * S_ + s0) * N_ + i];
    __syncthreads();
    int lane = tid & 63, wave = tid >> 6;
    int ml = wave * 16 + (lane & 15);
    int m  = m0 + ml;
    int n0 = (lane >> 4) * 4;
    float Aa[4], h[4] = {0,0,0,0}, g[4] = {1.f,1.f,1.f,1.f};
#pragma unroll
    for (int j = 0; j < 4; ++j) {
        float a = -expf(A_log[(size_t)(n0 + j) * M_ + m]);
        Aa[j] = fminf(fmaxf(a, -10.f), -1e-6f);
    }
    for (int s = 0; s < CH; ++s) {
        float dtv = ldsDt[s * 64 + ml];
        float uv  = ldsU [s * 64 + ml];
        float du  = dtv * uv;
        float4 bv = *reinterpret_cast<const float4*>(&ldsB[s * 16 + n0]);
        float bb[4] = {bv.x, bv.y, bv.z, bv.w};
#pragma unroll
        for (int j = 0; j < 4; ++j) {
            float ea = __expf(dtv * Aa[j]);
            h[j] = fmaf(ea, h[j], g[j] * (du * bb[j]));
            g[j] *= ea;
        }
    }
#pragma unroll
    for (int j = 0; j < 4; ++j) {
        size_t o = ((size_t)(b * 16 + n0 + j) * NC + c) * M_ + m;
        P[o] = g[j];
        H[o] = h[j];
    }
}

// pass2: compose across chunks; P[c],H[c] become exclusive (g_init, h_init):
//   g_run=1, h_run=0; per c: h_run = Pc*h_run + g_run*Hloc; g_run *= Pc
__global__ __launch_bounds__(256) void k_pass2(float* __restrict__ P,
                                               float* __restrict__ H) {
    int idx = blockIdx.x * 256 + threadIdx.x;          // 0..32767
    int m = idx & (M_ - 1);
    int n = (idx >> 10) & 15;
    int b = idx >> 14;
    size_t base = ((size_t)(b * 16 + n) * NC) * M_ + m;
    float grun = 1.f, hrun = 0.f;
#pragma unroll 1
    for (int c0 = 0; c0 < NC; c0 += 8) {
        float pv[8], hv[8];
#pragma unroll
        for (int t = 0; t < 8; ++t) {
            pv[t] = P[base + (size_t)(c0 + t) * M_];
            hv[t] = H[base + (size_t)(c0 + t) * M_];
        }
#pragma unroll
        for (int t = 0; t < 8; ++t) {
            P[base + (size_t)(c0 + t) * M_] = grun;
            H[base + (size_t)(c0 + t) * M_] = hrun;
            hrun = fmaf(pv[t], hrun, grun * hv[t]);
            grun *= pv[t];
        }
    }
}

// pass3: (g,h) from inits; ea=e^a; h = ea*h + g*du*b; g *= ea; y = sum_n h*C
// grid (16, NC, B_), block 256; 4 n-states per thread, y via shfl_xor
__global__ __launch_bounds__(256) void k_pass3(const float* __restrict__ dt,
                                               const float* __restrict__ u,
                                               const float* __restrict__ Bp,
                                               const float* __restrict__ Cp,
                                               const float* __restrict__ A_log,
                                               const float* __restrict__ Dskip,
                                               const float* __restrict__ Pinit,
                                               const float* __restrict__ Hinit,
                                               float* __restrict__ out) {
    __shared__ float ldsDt[CH * 64], ldsU[CH * 64], ldsB[CH * 16], ldsC[CH * 16];
    int m0 = blockIdx.x * 64, c = blockIdx.y, b = blockIdx.z;
    int s0 = c * CH;
    int tid = threadIdx.x;
    for (int i = tid; i < CH * 64; i += 256) {
        int s = i >> 6, ml = i & 63;
        size_t off = ((size_t)(b * S_ + s0 + s)) * M_ + m0 + ml;
        ldsDt[i] = dt[off];
        ldsU[i]  = u[off];
    }
    for (int i = tid; i < CH * 16; i += 256) {
        ldsB[i] = Bp[(size_t)(b * S_ + s0) * N_ + i];
        ldsC[i] = Cp[(size_t)(b * S_ + s0) * N_ + i];
    }
    __syncthreads();
    int lane = tid & 63, wave = tid >> 6;
    int ml = wave * 16 + (lane & 15);
    int m  = m0 + ml;
    int ng = lane >> 4, n0 = ng * 4;
    float Aa[4], h[4], g[4];
#pragma unroll
    for (int j = 0; j < 4; ++j) {
        float a = -expf(A_log[(size_t)(n0 + j) * M_ + m]);
        Aa[j] = fminf(fmaxf(a, -10.f), -1e-6f);
        size_t o = ((size_t)(b * 16 + n0 + j) * NC + c) * M_ + m;
        g[j] = Pinit[o];
        h[j] = Hinit[o];
    }
    float Dm = Dskip[m];
    for (int s = 0; s < CH; ++s) {
        float dtv = ldsDt[s * 64 + ml];
        float uv  = ldsU [s * 64 + ml];
        float du  = dtv * uv;
        float4 bv = *reinterpret_cast<const float4*>(&ldsB[s * 16 + n0]);
        float4 cv = *reinterpret_cast<const float4*>(&ldsC[s * 16 + n0]);
        float bb[4] = {bv.x, bv.y, bv.z, bv.w};
        float cc[4] = {cv.x, cv.y, cv.z, cv.w};
        float y = 0.f;
#pragma unroll
        for (int j = 0; j < 4; ++j) {
            float ea = __expf(dtv * Aa[j]);
            h[j] = fmaf(ea, h[j], g[j] * (du * bb[j]));
            g[j] *= ea;
            y = fmaf(h[j], cc[j], y);
        }
        y += __shfl_xor(y, 16, 64);
        y += __shfl_xor(y, 32, 64);
        if (ng == 0) {
            float o = y + uv * Dm;
            o = fminf(fmaxf(o, -10000.f), 10000.f);
            out[((size_t)(b * S_ + s0 + s)) * M_ + m] = o;
        }
    }
}

extern "C" void kernel_launch(void* const* d_in, const int* in_sizes, int n_in,
                              void* d_out, int out_size, void* d_ws, size_t ws_size,
                              hipStream_t stream) {
    const float* u     = (const float*)d_in[0];
    const float* delta = (const float*)d_in[1];
    const float* Wdt   = (const float*)d_in[2];
    const float* bdt   = (const float*)d_in[3];
    const float* A_log = (const float*)d_in[4];
    const float* Dski  = (const float*)d_in[5];
    const float* Bw    = (const float*)d_in[6];
    const float* Cw    = (const float*)d_in[7];
    float* out = (float*)d_out;
    float* ws  = (float*)d_ws;

    float* dt  = ws + DT_OFF;
    float* P   = ws + P_OFF;
    float* H   = ws + H_OFF;
    float* Bp  = ws + BP_OFF;
    float* Cp  = ws + CP_OFF;
    float* BwT = ws + BWT_OFF;
    float* CwT = ws + CWT_OFF;
    float* pB  = ws + PB_OFF;
    float* pC  = ws + PC_OFF;

    k_prep<<<64, 256, 0, stream>>>(Bw, Cw, BwT, CwT);
    k_dt<<<dim3(4, 512), 256, 0, stream>>>(delta, Wdt, bdt, dt);
    k_bc_partial<<<dim3(256, 4), 256, 0, stream>>>(u, BwT, CwT, pB, pC);
    k_bc_reduce<<<256, 256, 0, stream>>>(pB, pC, Bp, Cp);
    k_pass1<<<dim3(16, NC, B_), 256, 0, stream>>>(dt, u, Bp, A_log, P, H);
    k_pass2<<<128, 256, 0, stream>>>(P, H);
    k_pass3<<<dim3(16, NC, B_), 256, 0, stream>>>(dt, u, Bp, Cp, A_log, Dski, P, H, out);
}

// Round 5
// 106.774 us; speedup vs baseline: 1.1987x; 1.0744x over previous
//
#include <hip/hip_runtime.h>
#include <hip/hip_bf16.h>
#include <math.h>

#define B_ 2
#define S_ 2048
#define M_ 1024
#define R_ 64
#define N_ 16
#define NC 64          // s-chunks
#define CH (S_/NC)     // 32

// ws float offsets
#define DT_OFF  0                    // 4,194,304
#define P_OFF   4194304              // 2,097,152  chunk prod of e^a -> g_init
#define H_OFF   6291456              // 2,097,152  Hloc -> h_init
#define BWT_OFF 8388608              // 16,384
#define CWT_OFF 8404992              // 16,384
#define PB_OFF  8421376              // 131,072 (2 k-split partials, B)
#define PC_OFF  8552448              // 131,072 (C)
// total 8,683,520 floats = 34.7 MiB

// dt = clip(softplus(delta @ Wdt^T + bdt), 1e-6, 10); grid (4, 512)
// also embeds the Bw/Cw transpose (8 elements per block, no sync needed:
// BwT/CwT are consumed by the NEXT kernel).
__global__ __launch_bounds__(256) void k_dt(const float* __restrict__ delta,
                                            const float* __restrict__ Wdt,
                                            const float* __restrict__ bdt,
                                            const float* __restrict__ Bw,
                                            const float* __restrict__ Cw,
                                            float* __restrict__ dt,
                                            float* __restrict__ BwT,
                                            float* __restrict__ CwT) {
    int bid = blockIdx.y * 4 + blockIdx.x;             // 0..2047
    if (threadIdx.x < 8) {
        int idx = bid * 8 + threadIdx.x;               // 0..16383
        int mt = idx >> 4, nt = idx & 15;
        BwT[idx] = Bw[nt * M_ + mt];
        CwT[idx] = Cw[nt * M_ + mt];
    }
    int m    = blockIdx.x * 256 + threadIdx.x;         // 0..1023
    int row0 = blockIdx.y * 8;                         // bs base
    float w[R_];
    const float4* W4 = reinterpret_cast<const float4*>(Wdt + (size_t)m * R_);
#pragma unroll
    for (int i = 0; i < R_ / 4; ++i) {
        float4 v = W4[i];
        w[4*i] = v.x; w[4*i+1] = v.y; w[4*i+2] = v.z; w[4*i+3] = v.w;
    }
    float bias = bdt[m];
#pragma unroll 1
    for (int r = 0; r < 8; ++r) {
        int bs = row0 + r;
        const float* dr = delta + (size_t)bs * R_;     // wave-uniform -> s_load
        float acc = bias;
#pragma unroll
        for (int k = 0; k < R_; ++k) acc = fmaf(dr[k], w[k], acc);
        float sp = fmaxf(acc, 0.f) + log1pf(expf(-fabsf(acc)));
        sp = fminf(fmaxf(sp, 1e-6f), 10.0f);
        dt[(size_t)bs * M_ + m] = sp;
    }
}

// B/C projection, 2-way K-split partials; grid (256 row-groups, 2 k-splits)
// partials are summed by pass1/pass3 during staging (no reduce kernel).
__global__ __launch_bounds__(256) void k_bc_partial(const float* __restrict__ u,
                                                    const float* __restrict__ BwT,
                                                    const float* __restrict__ CwT,
                                                    float* __restrict__ pB,
                                                    float* __restrict__ pC) {
    __shared__ float uLds[16 * 516];                   // 16 rows x 512 k, pad +4
    int r0 = blockIdx.x * 16;
    int k0 = blockIdx.y * 512;
    for (int i = threadIdx.x; i < 2048; i += 256) {    // 2048 float4s
        int r = i >> 7, kq = i & 127;
        float4 v = *reinterpret_cast<const float4*>(&u[(size_t)(r0 + r) * M_ + k0 + kq * 4]);
        *reinterpret_cast<float4*>(&uLds[r * 516 + kq * 4]) = v;
    }
    __syncthreads();
    int r = threadIdx.x >> 4, n = threadIdx.x & 15;
    const float4* u4 = reinterpret_cast<const float4*>(uLds + r * 516);
    float accB = 0.f, accC = 0.f;
#pragma unroll 4
    for (int k4 = 0; k4 < 128; ++k4) {
        float4 uv = u4[k4];
        int kb = k0 + k4 * 4;
        accB = fmaf(uv.x, BwT[(kb+0)*16 + n], accB);
        accB = fmaf(uv.y, BwT[(kb+1)*16 + n], accB);
        accB = fmaf(uv.z, BwT[(kb+2)*16 + n], accB);
        accB = fmaf(uv.w, BwT[(kb+3)*16 + n], accB);
        accC = fmaf(uv.x, CwT[(kb+0)*16 + n], accC);
        accC = fmaf(uv.y, CwT[(kb+1)*16 + n], accC);
        accC = fmaf(uv.z, CwT[(kb+2)*16 + n], accC);
        accC = fmaf(uv.w, CwT[(kb+3)*16 + n], accC);
    }
    size_t o = (size_t)blockIdx.y * 65536 + (size_t)(r0 + r) * 16 + n;
    pB[o] = accB;
    pC[o] = accC;
}

// pass1: per-chunk Pc = prod(e^a) and Hloc from (g=1, h=0):
//   ea = e^a; h = ea*h + g*du*b; g *= ea
// grid (16, NC, B_), block 256; 4 n-states per thread
__global__ __launch_bounds__(256) void k_pass1(const float* __restrict__ dt,
                                               const float* __restrict__ u,
                                               const float* __restrict__ pB,
                                               const float* __restrict__ A_log,
                                               float* __restrict__ P,
                                               float* __restrict__ H) {
    __shared__ float ldsDt[CH * 64], ldsU[CH * 64], ldsB[CH * 16];
    int m0 = blockIdx.x * 64, c = blockIdx.y, b = blockIdx.z;
    int s0 = c * CH;
    int tid = threadIdx.x;
    for (int i = tid; i < 512; i += 256) {             // float4 staging
        int s = i >> 4, mq = (i & 15) * 4;
        size_t off = ((size_t)(b * S_ + s0 + s)) * M_ + m0 + mq;
        *reinterpret_cast<float4*>(&ldsDt[s * 64 + mq]) = *reinterpret_cast<const float4*>(&dt[off]);
        *reinterpret_cast<float4*>(&ldsU [s * 64 + mq]) = *reinterpret_cast<const float4*>(&u[off]);
    }
    {
        size_t base = (size_t)(b * S_ + s0) * N_;
        for (int i = tid; i < CH * 16; i += 256)
            ldsB[i] = pB[base + i] + pB[65536 + base + i];
    }
    __syncthreads();
    int lane = tid & 63, wave = tid >> 6;
    int ml = wave * 16 + (lane & 15);
    int m  = m0 + ml;
    int n0 = (lane >> 4) * 4;
    float Aa[4], h[4] = {0,0,0,0}, g[4] = {1.f,1.f,1.f,1.f};
#pragma unroll
    for (int j = 0; j < 4; ++j) {
        float a = -expf(A_log[(size_t)(n0 + j) * M_ + m]);
        Aa[j] = fminf(fmaxf(a, -10.f), -1e-6f);
    }
    for (int s = 0; s < CH; ++s) {
        float dtv = ldsDt[s * 64 + ml];
        float uv  = ldsU [s * 64 + ml];
        float du  = dtv * uv;
        float4 bv = *reinterpret_cast<const float4*>(&ldsB[s * 16 + n0]);
        float bb[4] = {bv.x, bv.y, bv.z, bv.w};
#pragma unroll
        for (int j = 0; j < 4; ++j) {
            float ea = __expf(dtv * Aa[j]);
            h[j] = fmaf(ea, h[j], g[j] * (du * bb[j]));
            g[j] *= ea;
        }
    }
#pragma unroll
    for (int j = 0; j < 4; ++j) {
        size_t o = ((size_t)(b * 16 + n0 + j) * NC + c) * M_ + m;
        P[o] = g[j];
        H[o] = h[j];
    }
}

// pass2: compose across chunks; P[c],H[c] become exclusive (g_init, h_init)
// grid 512 x 64 threads (spread over all CUs)
__global__ __launch_bounds__(64) void k_pass2(float* __restrict__ P,
                                              float* __restrict__ H) {
    int idx = blockIdx.x * 64 + threadIdx.x;           // 0..32767
    int m = idx & (M_ - 1);
    int n = (idx >> 10) & 15;
    int b = idx >> 14;
    size_t base = ((size_t)(b * 16 + n) * NC) * M_ + m;
    float grun = 1.f, hrun = 0.f;
#pragma unroll 1
    for (int c0 = 0; c0 < NC; c0 += 8) {
        float pv[8], hv[8];
#pragma unroll
        for (int t = 0; t < 8; ++t) {
            pv[t] = P[base + (size_t)(c0 + t) * M_];
            hv[t] = H[base + (size_t)(c0 + t) * M_];
        }
#pragma unroll
        for (int t = 0; t < 8; ++t) {
            P[base + (size_t)(c0 + t) * M_] = grun;
            H[base + (size_t)(c0 + t) * M_] = hrun;
            hrun = fmaf(pv[t], hrun, grun * hv[t]);
            grun *= pv[t];
        }
    }
}

// pass3: (g,h) from inits; ea=e^a; h = ea*h + g*du*b; g *= ea; y = sum_n h*C
// grid (16, NC, B_), block 256; 4 n-states per thread, y via shfl_xor
__global__ __launch_bounds__(256) void k_pass3(const float* __restrict__ dt,
                                               const float* __restrict__ u,
                                               const float* __restrict__ pB,
                                               const float* __restrict__ pC,
                                               const float* __restrict__ A_log,
                                               const float* __restrict__ Dskip,
                                               const float* __restrict__ Pinit,
                                               const float* __restrict__ Hinit,
                                               float* __restrict__ out) {
    __shared__ float ldsDt[CH * 64], ldsU[CH * 64], ldsB[CH * 16], ldsC[CH * 16];
    int m0 = blockIdx.x * 64, c = blockIdx.y, b = blockIdx.z;
    int s0 = c * CH;
    int tid = threadIdx.x;
    for (int i = tid; i < 512; i += 256) {             // float4 staging
        int s = i >> 4, mq = (i & 15) * 4;
        size_t off = ((size_t)(b * S_ + s0 + s)) * M_ + m0 + mq;
        *reinterpret_cast<float4*>(&ldsDt[s * 64 + mq]) = *reinterpret_cast<const float4*>(&dt[off]);
        *reinterpret_cast<float4*>(&ldsU [s * 64 + mq]) = *reinterpret_cast<const float4*>(&u[off]);
    }
    {
        size_t base = (size_t)(b * S_ + s0) * N_;
        for (int i = tid; i < CH * 16; i += 256) {
            ldsB[i] = pB[base + i] + pB[65536 + base + i];
            ldsC[i] = pC[base + i] + pC[65536 + base + i];
        }
    }
    __syncthreads();
    int lane = tid & 63, wave = tid >> 6;
    int ml = wave * 16 + (lane & 15);
    int m  = m0 + ml;
    int ng = lane >> 4, n0 = ng * 4;
    float Aa[4], h[4], g[4];
#pragma unroll
    for (int j = 0; j < 4; ++j) {
        float a = -expf(A_log[(size_t)(n0 + j) * M_ + m]);
        Aa[j] = fminf(fmaxf(a, -10.f), -1e-6f);
        size_t o = ((size_t)(b * 16 + n0 + j) * NC + c) * M_ + m;
        g[j] = Pinit[o];
        h[j] = Hinit[o];
    }
    float Dm = Dskip[m];
    for (int s = 0; s < CH; ++s) {
        float dtv = ldsDt[s * 64 + ml];
        float uv  = ldsU [s * 64 + ml];
        float du  = dtv * uv;
        float4 bv = *reinterpret_cast<const float4*>(&ldsB[s * 16 + n0]);
        float4 cv = *reinterpret_cast<const float4*>(&ldsC[s * 16 + n0]);
        float bb[4] = {bv.x, bv.y, bv.z, bv.w};
        float cc[4] = {cv.x, cv.y, cv.z, cv.w};
        float y = 0.f;
#pragma unroll
        for (int j = 0; j < 4; ++j) {
            float ea = __expf(dtv * Aa[j]);
            h[j] = fmaf(ea, h[j], g[j] * (du * bb[j]));
            g[j] *= ea;
            y = fmaf(h[j], cc[j], y);
        }
        y += __shfl_xor(y, 16, 64);
        y += __shfl_xor(y, 32, 64);
        if (ng == 0) {
            float o = y + uv * Dm;
            o = fminf(fmaxf(o, -10000.f), 10000.f);
            out[((size_t)(b * S_ + s0 + s)) * M_ + m] = o;
        }
    }
}

extern "C" void kernel_launch(void* const* d_in, const int* in_sizes, int n_in,
                              void* d_out, int out_size, void* d_ws, size_t ws_size,
                              hipStream_t stream) {
    const float* u     = (const float*)d_in[0];
    const float* delta = (const float*)d_in[1];
    const float* Wdt   = (const float*)d_in[2];
    const float* bdt   = (const float*)d_in[3];
    const float* A_log = (const float*)d_in[4];
    const float* Dski  = (const float*)d_in[5];
    const float* Bw    = (const float*)d_in[6];
    const float* Cw    = (const float*)d_in[7];
    float* out = (float*)d_out;
    float* ws  = (float*)d_ws;

    float* dt  = ws + DT_OFF;
    float* P   = ws + P_OFF;
    float* H   = ws + H_OFF;
    float* BwT = ws + BWT_OFF;
    float* CwT = ws + CWT_OFF;
    float* pB  = ws + PB_OFF;
    float* pC  = ws + PC_OFF;

    k_dt<<<dim3(4, 512), 256, 0, stream>>>(delta, Wdt, bdt, Bw, Cw, dt, BwT, CwT);
    k_bc_partial<<<dim3(256, 2), 256, 0, stream>>>(u, BwT, CwT, pB, pC);
    k_pass1<<<dim3(16, NC, B_), 256, 0, stream>>>(dt, u, pB, A_log, P, H);
    k_pass2<<<512, 64, 0, stream>>>(P, H);
    k_pass3<<<dim3(16, NC, B_), 256, 0, stream>>>(dt, u, pB, pC, A_log, Dski, P, H, out);
}